// Round 2
// baseline (199.108 us; speedup 1.0000x reference)
//
#include <hip/hip_runtime.h>

typedef __attribute__((ext_vector_type(8))) short short8;
typedef __attribute__((ext_vector_type(4))) float f32x4;
typedef unsigned short u16;

#define NE2 65536
#define NBLK 256

__device__ __forceinline__ u16 f2bf_rne(float x) {
  union { float f; unsigned int u; } v; v.f = x;
  unsigned int r = v.u + 0x7fffu + ((v.u >> 16) & 1u);
  return (u16)(r >> 16);
}

// ---------------------------------------------------------------------------
// Manual grid barrier: monotonic counter, device-scope atomics + fences.
// All NBLK blocks are co-resident (1 block/CU, grid=256 <= 256 CUs).
// ---------------------------------------------------------------------------
__device__ __forceinline__ void grid_barrier(unsigned int* cnt, unsigned int target) {
  __syncthreads();
  if (threadIdx.x == 0) {
    __threadfence();   // release: flush stores device-wide
    __hip_atomic_fetch_add(cnt, 1u, __ATOMIC_ACQ_REL, __HIP_MEMORY_SCOPE_AGENT);
    unsigned int spins = 0;
    while (__hip_atomic_load(cnt, __ATOMIC_ACQUIRE, __HIP_MEMORY_SCOPE_AGENT) < target) {
      __builtin_amdgcn_s_sleep(2);
      if (++spins > 100000000u) break;   // failsafe: avoid infinite hang
    }
    __threadfence();   // acquire: invalidate caches before post-barrier loads
  }
  __syncthreads();
}

// ---------------------------------------------------------------------------
// 256-thread-team MFMA GEMM building block (64x64 tile, K=256 fixed, LDS
// double-buffered, 1 barrier/iter). All teams in a block execute the SAME
// 8-iteration barrier loop (inactive teams just hit the barriers).
// C[r,c] (+)= sum_k A[r, aoff+k] * (transB ? B[boff+k, c] : B[c, boff+k])
// ---------------------------------------------------------------------------
struct QJob {
  const float* A; const float* B; const float* bias;
  float* Cf; u16* Cb;
  int lda, aoff, ldb, boff, transB, K, ldc, coff, atomicC;
};
struct QS { float4 a0, a1, b0, b1; };

__device__ __forceinline__ void q_load(const QJob& job, int m0, int n0,
                                       int sr, int sk, int tk, int tc,
                                       int kt, QS& s) {
  const int k0 = kt << 5;
  const float* ap = job.A + (size_t)(m0 + sr) * job.lda + job.aoff + k0 + sk * 8;
  s.a0 = *(const float4*)ap; s.a1 = *(const float4*)(ap + 4);
  if (!job.transB) {
    const float* bp = job.B + (size_t)(n0 + sr) * job.ldb + job.boff + k0 + sk * 8;
    s.b0 = *(const float4*)bp; s.b1 = *(const float4*)(bp + 4);
  } else {
    const float* bp = job.B + (size_t)(job.boff + k0 + tk) * job.ldb + n0 + tc;
    s.b0 = *(const float4*)bp; s.b1 = *(const float4*)(bp + 4);
  }
}

__device__ __forceinline__ void q_store(const QJob& job, const QS& s,
                                        int sr, int sps, int tk, int tc,
                                        u16 (&As)[64][32], u16 (&Bs)[64][32]) {
  float av[8] = {s.a0.x, s.a0.y, s.a0.z, s.a0.w, s.a1.x, s.a1.y, s.a1.z, s.a1.w};
  union { u16 us[8]; uint4 u4; } pk;
#pragma unroll
  for (int j = 0; j < 8; ++j) pk.us[j] = f2bf_rne(av[j]);
  *(uint4*)&As[sr][sps] = pk.u4;
  float bv[8] = {s.b0.x, s.b0.y, s.b0.z, s.b0.w, s.b1.x, s.b1.y, s.b1.z, s.b1.w};
  if (!job.transB) {
    union { u16 us[8]; uint4 u4; } pk2;
#pragma unroll
    for (int j = 0; j < 8; ++j) pk2.us[j] = f2bf_rne(bv[j]);
    *(uint4*)&Bs[sr][sps] = pk2.u4;
  } else {
#pragma unroll
    for (int j = 0; j < 8; ++j)
      Bs[tc + j][((tk >> 3) ^ (j & 3)) * 8 + (tk & 7)] = f2bf_rne(bv[j]);
  }
}

__device__ __forceinline__ void run_qteam(const QJob& job, bool act,
                                          int m0, int n0, int tid,
                                          u16 (*As2)[64][32], u16 (*Bs2)[64][32]) {
  const int lane = tid & 63, w = tid >> 6;
  const int wr = w >> 1, wc = w & 1;
  const int q = lane >> 4, l15 = lane & 15;
  const int qs = (q ^ (l15 & 3)) * 8;
  const int sr = tid >> 2, sk = tid & 3;
  const int sps = (sk ^ (sr & 3)) * 8;
  const int tk = tid >> 3, tc = (tid & 7) * 8;

  f32x4 acc[2][2];
#pragma unroll
  for (int a = 0; a < 2; ++a)
#pragma unroll
    for (int c = 0; c < 2; ++c) acc[a][c] = (f32x4){0.f, 0.f, 0.f, 0.f};

  QS s;
  if (act) {
    q_load(job, m0, n0, sr, sk, tk, tc, 0, s);
    q_store(job, s, sr, sps, tk, tc, As2[0], Bs2[0]);
    q_load(job, m0, n0, sr, sk, tk, tc, 1, s);
  }

  for (int kt = 0; kt < 8; ++kt) {
    __syncthreads();
    if (act) {
      const int cur = kt & 1;
      short8 aF[2], bF[2];
#pragma unroll
      for (int t = 0; t < 2; ++t)
        aF[t] = *(const short8*)&As2[cur][wr * 32 + t * 16 + l15][qs];
#pragma unroll
      for (int t = 0; t < 2; ++t)
        bF[t] = *(const short8*)&Bs2[cur][wc * 32 + t * 16 + l15][qs];
      if (kt + 1 < 8)
        q_store(job, s, sr, sps, tk, tc, As2[cur ^ 1], Bs2[cur ^ 1]);
#pragma unroll
      for (int tm = 0; tm < 2; ++tm)
#pragma unroll
        for (int tn = 0; tn < 2; ++tn)
          acc[tm][tn] = __builtin_amdgcn_mfma_f32_16x16x32_bf16(aF[tm], bF[tn], acc[tm][tn], 0, 0, 0);
      if (kt + 2 < 8)
        q_load(job, m0, n0, sr, sk, tk, tc, kt + 2, s);
    }
  }
  if (!act) return;

  float bv[2] = {0.f, 0.f};
  if (job.bias != nullptr) {
#pragma unroll
    for (int tn = 0; tn < 2; ++tn)
      bv[tn] = job.bias[n0 + wc * 32 + tn * 16 + l15];
  }
#pragma unroll
  for (int tm = 0; tm < 2; ++tm) {
#pragma unroll
    for (int r = 0; r < 4; ++r) {
      const int row = m0 + wr * 32 + tm * 16 + q * 4 + r;
#pragma unroll
      for (int tn = 0; tn < 2; ++tn) {
        const int col = n0 + wc * 32 + tn * 16 + l15;
        const float v = acc[tm][tn][r] + bv[tn];
        if (job.atomicC) {
          atomicAdd(job.Cf + (size_t)row * job.ldc + job.coff + col, v);
        } else if (job.Cb != nullptr) {
          job.Cb[(size_t)row * job.ldc + job.coff + col] = f2bf_rne(v);
        } else {
          job.Cf[(size_t)row * job.ldc + job.coff + col] = v;
        }
      }
    }
  }
}

struct MegaArgs {
  QJob a[10];   // phase A: 160 tile-tasks
  QJob b[6];    // phase B: 96 tile-tasks (C1 split into 2 K-halves, atomic)
  const float* encJ;
  const u16* T1; const u16* T2; const u16* Q1a; const u16* Q1v;
  const u16* Wcat; const float* C1m;
  const float* fc2_w; const float* fc2_b;
  float* out;
  unsigned int* bar;
};

// ---------------------------------------------------------------------------
// One kernel, normal launch: phase A -> barrier -> phase B -> barrier ->
// phase C (fused main GEMM, one batch b per block, 256x256 tile, 16 waves).
// 256 blocks x 1024 thr, 64 KB LDS, 1 block/CU -> all blocks co-resident.
// ---------------------------------------------------------------------------
__global__ __launch_bounds__(1024, 4) void mega_kernel(MegaArgs M) {
  __shared__ __align__(16) u16 smem[32768];   // 64 KB, carved per phase

  const int tid1024 = threadIdx.x;
  const int team = tid1024 >> 8;     // 4 teams of 256 for phases A/B
  const int tid = tid1024 & 255;

  u16 (*tAs)[64][32] = (u16 (*)[64][32])(smem + team * 8192);
  u16 (*tBs)[64][32] = (u16 (*)[64][32])(smem + team * 8192 + 4096);

  // ---- Phase A: encJ (3-way K-split atomics), Mca, Mcv, Wcat ----
  {
    const int task = (int)blockIdx.x + NBLK * team;   // spread over blocks
    const bool act = task < 160;
    const QJob job = M.a[act ? (task >> 4) : 0];
    const int tile = task & 15;
    run_qteam(job, act, (tile >> 2) * 64, (tile & 3) * 64, tid, tAs, tBs);
  }
  grid_barrier(M.bar, NBLK);

  // ---- Phase B: T1, T2, Q1a, Q1v, C1 (2-way K-split atomics) ----
  {
    const int task = (int)blockIdx.x + NBLK * team;
    const bool act = task < 96;
    const QJob job = M.b[act ? (task >> 4) : 0];
    const int tile = task & 15;
    run_qteam(job, act, (tile >> 2) * 64, (tile & 3) * 64, tid, tAs, tBs);
  }
  grid_barrier(M.bar, 2 * NBLK);

  // ---- Phase C: fused main GEMM, one batch per block (256m x 256n) ----
  {
    u16 (*FAs)[256][32] = (u16 (*)[256][32])(smem);            // 32 KB
    u16 (*FBs)[256][32] = (u16 (*)[256][32])(smem + 16384);    // 32 KB

    const int b = blockIdx.x;

    const int lane = tid1024 & 63;
    const int w = tid1024 >> 6;        // 0..15
    const int wm = w >> 2, wn = w & 3; // 4x4 wave grid of 64x64 tiles
    const int q = lane >> 4, l15 = lane & 15;
    const int qs = (q ^ (l15 & 3)) * 8;

    // A-gen mapping: 1024 thr cover 256 rows x 4 k-slots
    const int am = tid1024 >> 2;       // row i, 0..255
    const int akq8 = tid1024 & 3;
    const int aps = (akq8 ^ (am & 3)) * 8;

    // B staging: 1024 thr cover 256 n-rows x 4 k-slots
    const int n0b = tid1024 >> 2;
    const int bk = tid1024 & 3;
    const int bsl = (bk ^ (n0b & 3)) * 8;

    const float e_a = 0.0625f * M.encJ[b * 512 + am];
    const float e_v = 0.0625f * M.encJ[b * 512 + 256 + am];

    f32x4 acc[4][4];
#pragma unroll
    for (int a = 0; a < 4; ++a)
#pragma unroll
      for (int c = 0; c < 4; ++c) acc[a][c] = (f32x4){0.f, 0.f, 0.f, 0.f};

    uint4 tR, qR, w0;   // in-flight data for the NEXT kc

    auto load_kc = [&](int kcl) {
      const u16* Tp = (kcl < 8) ? M.T1 : M.T2;
      const u16* Qp = (kcl < 8) ? M.Q1a : M.Q1v;
      const int col = (kcl & 7) * 32 + akq8 * 8;
      tR = *(const uint4*)(Tp + am * 256 + col);
      qR = *(const uint4*)(Qp + b * 256 + col);
      w0 = *(const uint4*)(M.Wcat + (size_t)n0b * 512 + kcl * 32 + bk * 8);
    };

    auto pack_store = [&](int kcl, int buf) {
      const float ee = (kcl < 8) ? e_a : e_v;
      unsigned int tw[4] = {tR.x, tR.y, tR.z, tR.w};
      unsigned int qw[4] = {qR.x, qR.y, qR.z, qR.w};
      unsigned int ow[4];
#pragma unroll
      for (int p = 0; p < 4; ++p) {
        float t0 = __uint_as_float(tw[p] << 16);
        float t1 = __uint_as_float(tw[p] & 0xffff0000u);
        float q0 = __uint_as_float(qw[p] << 16);
        float q1 = __uint_as_float(qw[p] & 0xffff0000u);
        float h0 = fmaxf(fmaf(ee, q0, t0), 0.f);
        float h1 = fmaxf(fmaf(ee, q1, t1), 0.f);
        unsigned int u0 = (__float_as_uint(h0) + 0x8000u) >> 16;
        unsigned int u1 = (__float_as_uint(h1) + 0x8000u) & 0xffff0000u;
        ow[p] = u0 | u1;
      }
      uint4 pk; pk.x = ow[0]; pk.y = ow[1]; pk.z = ow[2]; pk.w = ow[3];
      *(uint4*)&FAs[buf][am][aps] = pk;
      *(uint4*)&FBs[buf][n0b][bsl] = w0;
    };

    load_kc(0);
    pack_store(0, 0);
    load_kc(1);

    for (int kc = 0; kc < 16; ++kc) {
      __syncthreads();
      const int cur = kc & 1;
      const u16* aBase = &FAs[cur][wm * 64][0];
      const u16* bBase = &FBs[cur][wn * 64][0];
      short8 aF[4];
#pragma unroll
      for (int t = 0; t < 4; ++t)
        aF[t] = *(const short8*)(aBase + (t * 16 + l15) * 32 + qs);
      if (kc < 15) pack_store(kc + 1, cur ^ 1);
#pragma unroll
      for (int tn = 0; tn < 4; ++tn) {
        short8 bF = *(const short8*)(bBase + (tn * 16 + l15) * 32 + qs);
#pragma unroll
        for (int tm = 0; tm < 4; ++tm)
          acc[tm][tn] = __builtin_amdgcn_mfma_f32_16x16x32_bf16(aF[tm], bF, acc[tm][tn], 0, 0, 0);
      }
      if (kc < 14) load_kc(kc + 2);
    }

    // epilogue: + C1, relu, * fc2, reduce over n.
    // red overlays FAs[0] (bytes [0,4K)) — disjoint from FAs[1]/FBs[1]
    // still being read for kc=15 MFMA by other waves.
    float (*red)[256] = (float (*)[256])smem;
    float fc2v[4];
#pragma unroll
    for (int tn = 0; tn < 4; ++tn)
      fc2v[tn] = M.fc2_w[wn * 64 + tn * 16 + l15];

#pragma unroll
    for (int tm = 0; tm < 4; ++tm) {
#pragma unroll
      for (int r = 0; r < 4; ++r) {
        const int mloc = wm * 64 + tm * 16 + q * 4 + r;   // = i
        float s = 0.f;
#pragma unroll
        for (int tn = 0; tn < 4; ++tn) {
          const int n = wn * 64 + tn * 16 + l15;
          float v = acc[tm][tn][r] + M.C1m[mloc * 256 + n];
          v = fmaxf(v, 0.f);
          s = fmaf(v, fc2v[tn], s);
        }
        s += __shfl_xor(s, 1);
        s += __shfl_xor(s, 2);
        s += __shfl_xor(s, 4);
        s += __shfl_xor(s, 8);
        if (l15 == 0) red[wn][mloc] = s;
      }
    }
    __syncthreads();
    if (tid1024 < 256) {
      M.out[b * 256 + tid1024] = M.fc2_b[0] + red[0][tid1024] + red[1][tid1024] +
                                 red[2][tid1024] + red[3][tid1024];
    }
  }
}

static QJob mkqjob(const float* A, const float* B, const float* bias,
                   float* Cf, u16* Cb,
                   int lda, int aoff, int ldb, int boff, int transB, int K,
                   int ldc, int coff, int atomicC) {
  QJob j;
  j.A = A; j.B = B; j.bias = bias; j.Cf = Cf; j.Cb = Cb;
  j.lda = lda; j.aoff = aoff; j.ldb = ldb; j.boff = boff; j.transB = transB;
  j.K = K; j.ldc = ldc; j.coff = coff; j.atomicC = atomicC;
  return j;
}

extern "C" void kernel_launch(void* const* d_in, const int* in_sizes, int n_in,
                              void* d_out, int out_size, void* d_ws, size_t ws_size,
                              hipStream_t stream) {
  const float* features1 = (const float*)d_in[0];
  const float* features2 = (const float*)d_in[1];
  const float* enc1_w = (const float*)d_in[2];
  const float* enc1_b = (const float*)d_in[3];
  const float* enc2_w = (const float*)d_in[4];
  const float* enc2_b = (const float*)d_in[5];
  const float* affa_w = (const float*)d_in[6];
  const float* affv_w = (const float*)d_in[7];
  const float* wa_w   = (const float*)d_in[8];
  const float* wv_w   = (const float*)d_in[9];
  const float* wca_w  = (const float*)d_in[10];
  const float* wcv_w  = (const float*)d_in[11];
  const float* wha_w  = (const float*)d_in[12];
  const float* whv_w  = (const float*)d_in[13];
  const float* fc1_w  = (const float*)d_in[14];
  const float* fc1_b  = (const float*)d_in[15];
  const float* fc2_w  = (const float*)d_in[16];
  const float* fc2_b  = (const float*)d_in[17];
  float* out = (float*)d_out;

  float* ws = (float*)d_ws;
  float* encJ = ws;                        // [256][512] fp32 (atomic-accumulated)
  float* McaF = ws + 2 * NE2;              // [256][256] fp32
  float* McvF = ws + 3 * NE2;
  float* C1m  = ws + 4 * NE2;              // [256][256] fp32 (atomic-accumulated)
  u16*   T1   = (u16*)(ws + 5 * NE2);      // [256][256] bf16
  u16*   T2   = T1 + NE2;
  u16*   Q1a  = (u16*)(ws + 6 * NE2);
  u16*   Q1v  = Q1a + NE2;
  u16*   Wcat = (u16*)(ws + 7 * NE2);      // [256][512] bf16
  unsigned int* bar = (unsigned int*)(ws + 8 * NE2);

  // zero atomic-accumulated regions (encJ..C1m) and the barrier counter
  hipMemsetAsync(ws, 0, (size_t)5 * NE2 * sizeof(float), stream);
  hipMemsetAsync(bar, 0, 64, stream);

  MegaArgs ma;
  // Phase A (all K=256): encJ via 3-way k-split atomics; Mca/Mcv; Wcat halves
  ma.a[0] = mkqjob(features1, enc1_w, enc1_b, encJ, nullptr, 768, 0,   768, 0,   0, 256, 512, 0, 1);
  ma.a[1] = mkqjob(features1, enc1_w, nullptr, encJ, nullptr, 768, 256, 768, 256, 0, 256, 512, 0, 1);
  ma.a[2] = mkqjob(features1, enc1_w, nullptr, encJ, nullptr, 768, 512, 768, 512, 0, 256, 512, 0, 1);
  ma.a[3] = mkqjob(features2, enc2_w, enc2_b, encJ, nullptr, 768, 0,   768, 0,   0, 256, 512, 256, 1);
  ma.a[4] = mkqjob(features2, enc2_w, nullptr, encJ, nullptr, 768, 256, 768, 256, 0, 256, 512, 256, 1);
  ma.a[5] = mkqjob(features2, enc2_w, nullptr, encJ, nullptr, 768, 512, 768, 512, 0, 256, 512, 256, 1);
  ma.a[6] = mkqjob(wca_w, affa_w, nullptr, McaF, nullptr, 256, 0, 256, 0, 1, 256, 256, 0, 0);
  ma.a[7] = mkqjob(wcv_w, affv_w, nullptr, McvF, nullptr, 256, 0, 256, 0, 1, 256, 256, 0, 0);
  ma.a[8] = mkqjob(fc1_w, wha_w, nullptr, nullptr, Wcat, 512, 0,   256, 0, 1, 256, 512, 0, 0);
  ma.a[9] = mkqjob(fc1_w, whv_w, nullptr, nullptr, Wcat, 512, 256, 256, 0, 1, 256, 512, 256, 0);
  // Phase B (all K=256): T1, T2, Q1a, Q1v; C1 as 2-way k-split atomics
  ma.b[0] = mkqjob(encJ, wa_w, nullptr, nullptr, T1,  512, 0,   256, 0,   0, 256, 256, 0, 0);
  ma.b[1] = mkqjob(encJ, wv_w, nullptr, nullptr, T2,  512, 256, 256, 0,   0, 256, 256, 0, 0);
  ma.b[2] = mkqjob(encJ, McaF, nullptr, nullptr, Q1a, 512, 0,   256, 0,   0, 256, 256, 0, 0);
  ma.b[3] = mkqjob(encJ, McvF, nullptr, nullptr, Q1v, 512, 256, 256, 0,   0, 256, 256, 0, 0);
  ma.b[4] = mkqjob(encJ, fc1_w, fc1_b,  C1m, nullptr, 512, 0,   512, 0,   0, 256, 256, 0, 1);
  ma.b[5] = mkqjob(encJ, fc1_w, nullptr, C1m, nullptr, 512, 256, 512, 256, 0, 256, 256, 0, 1);

  ma.encJ = encJ; ma.T1 = T1; ma.T2 = T2; ma.Q1a = Q1a; ma.Q1v = Q1v;
  ma.Wcat = Wcat; ma.C1m = C1m; ma.fc2_w = fc2_w; ma.fc2_b = fc2_b; ma.out = out;
  ma.bar = bar;

  hipLaunchKernelGGL(mega_kernel, dim3(NBLK), dim3(1024), 0, stream, ma);
}